// Round 11
// baseline (2908.372 us; speedup 1.0000x reference)
//
#include <hip/hip_runtime.h>
#include <stdint.h>

// PolicyCoreRNN: LSTM, B=1024, T=64, H=I=512.
// Round 11: de-serialize the per-step latency chain in persist_lock.
// (1) fast sigm/tanh (__expf + v_rcp) -- tanhf was precise-libm, ~40 instr.
// (2) xproj prefetched ONE STEP ahead (xq regs) -- HBM latency off the path.
// (3) per-wave spin (no block barrier after); order: arrive -> outputs ->
//     spin -> A-loads(t+1) -> lgkm-only join. (4) Hl/Cl pitch 40->36
//     (2-way free bank pattern on cell writes).

// ---------- round-1 (fallback) ws layout ----------
#define WC_OFF   0u
#define HF_OFF   4194304u
#define CF_OFF   5242880u
#define BIAS_OFF 7340032u
// ---------- fast-path ws layout (bytes) ----------
#define F_WIH   0u           // 2 MiB  bf16 W_ih frags (cb*16+ks)*1024
#define F_WHH   2097152u     // 2 MiB  bf16 W_hh frags
#define F_HF0   4194304u     // 1 MiB  h frags buf0, SPLIT u64 layout
#define F_HF1   5242880u     // 1 MiB  h frags buf1
#define F_BIAS  6291456u     // 8 KiB  f32 b_ih+b_hh
#define F_CTR   6299648u     // 16 barrier counters, 128B apart
#define F_XBF   7340032u     // 64 MiB bf16 x frags ((t*64+mb)*16+ks)*1024
#define F_XPROJ 74448896u    // 256 MiB bf16 x_proj D-frags ((t*64+mb)*128+n)*512
#define F_NEED  342884352u
// out (f32 elements): x | new_rnn_states | h_stack | c_stack
#define OUT_RNN  33554432u
#define OUT_HS   34603008u
#define OUT_CS   68157440u

typedef __attribute__((ext_vector_type(4))) float f32x4;
typedef __attribute__((ext_vector_type(8))) short s16x8;
typedef __attribute__((ext_vector_type(4))) unsigned int u32x4;
typedef __attribute__((ext_vector_type(4))) unsigned short u16x4;

__device__ __forceinline__ unsigned short f2bf(float f) {
  union { float f; unsigned int u; } v; v.f = f;
  return (unsigned short)((v.u + 0x7FFFu + ((v.u >> 16) & 1u)) >> 16);
}
__device__ __forceinline__ float bf2f(unsigned short s) {
  union { unsigned int u; float f; } v; v.u = ((unsigned int)s) << 16;
  return v.f;
}
__device__ __forceinline__ unsigned int pack2(float a, float b) {
  return (unsigned int)f2bf(a) | ((unsigned int)f2bf(b) << 16);
}
__device__ __forceinline__ float sigm(float x) { return 1.0f / (1.0f + __expf(-x)); }
// fast approximations (persist kernel only; ~1e-5 rel err, ok for bf16 out)
__device__ __forceinline__ float frcp(float x) { return __builtin_amdgcn_rcpf(x); }
__device__ __forceinline__ float sigm_f(float x) { return frcp(1.0f + __expf(-x)); }
__device__ __forceinline__ float tanh_f(float x) {
  return 1.0f - 2.0f * frcp(1.0f + __expf(2.0f * x));
}

__device__ __forceinline__ void gl_lds16(const void* g, void* lds) {
  __builtin_amdgcn_global_load_lds(
      (const __attribute__((address_space(1))) unsigned int*)g,
      (__attribute__((address_space(3))) unsigned int*)lds, 16, 0, 0);
}

// raw join barrier: drain LDS ops only (NOT vmcnt -> stores keep draining)
__device__ __forceinline__ void lds_barrier() {
  asm volatile("s_waitcnt lgkmcnt(0)" ::: "memory");
  __builtin_amdgcn_sched_barrier(0);
  __builtin_amdgcn_s_barrier();
}

// Fragment conventions (16x16x32 bf16 MFMA):
//  A/B input frag (1KB): lane l holds index (l&15) of the 16-dim, k = ks*32+(l>>4)*8+e.
//  D frag: col = l&15 (B dim), row = (l>>4)*4 + reg (A dim).  [m89-verified]
// h-exchange frag SPLIT layout (per frag f, 128 u64): hq[f*128 + l] = lane l
// elems e0..3 (low u64); hq[f*128 + 64 + l] = elems e4..7 (high u64).

// ====================== FAST PATH ======================

__global__ void __launch_bounds__(256) prep_fast(
    const float* __restrict__ xg, const float* __restrict__ rnn,
    const float* __restrict__ Wih, const float* __restrict__ Whh,
    const float* __restrict__ bih, const float* __restrict__ bhh,
    unsigned char* __restrict__ ws) {
  unsigned int tid = blockIdx.x * 256u + threadIdx.x;
  unsigned short* wih_f = (unsigned short*)(ws + F_WIH);
  unsigned short* whh_f = (unsigned short*)(ws + F_WHH);
  float* bias = (float*)(ws + F_BIAS);
  unsigned short* xbf = (unsigned short*)(ws + F_XBF);
  if (tid < 131072u) {
    unsigned int frag = tid >> 6, l = tid & 63u;
    unsigned int cb = frag >> 4, ks = frag & 15u;
    unsigned int g  = cb * 16u + (l & 15u);
    unsigned int k0 = ks * 32u + ((l >> 4) << 3);
    const float* src = Wih + (size_t)g * 512u + k0;
    u32x4 p;
    p.x = pack2(src[0], src[1]); p.y = pack2(src[2], src[3]);
    p.z = pack2(src[4], src[5]); p.w = pack2(src[6], src[7]);
    *(u32x4*)(wih_f + (size_t)frag * 512u + l * 8u) = p;
  } else if (tid < 262144u) {
    unsigned int t2 = tid - 131072u;
    unsigned int frag = t2 >> 6, l = t2 & 63u;
    unsigned int cb = frag >> 4, ks = frag & 15u;
    unsigned int g  = cb * 16u + (l & 15u);
    unsigned int k0 = ks * 32u + ((l >> 4) << 3);
    const float* src = Whh + (size_t)g * 512u + k0;
    u32x4 p;
    p.x = pack2(src[0], src[1]); p.y = pack2(src[2], src[3]);
    p.z = pack2(src[4], src[5]); p.w = pack2(src[6], src[7]);
    *(u32x4*)(whh_f + (size_t)frag * 512u + l * 8u) = p;
  } else if (tid < 327680u) {
    // h0 frags, SPLIT layout
    unsigned int t2 = tid - 262144u;
    unsigned int frag = t2 >> 6, l = t2 & 63u;
    unsigned int mb = frag >> 4, ks = frag & 15u;
    unsigned int b  = mb * 16u + (l & 15u);
    unsigned int c0 = ks * 32u + ((l >> 4) << 3);
    const float* src = rnn + (size_t)b * 1024u + c0;
    union { u32x4 v; unsigned long long q[2]; } u;
    u.v.x = pack2(src[0], src[1]); u.v.y = pack2(src[2], src[3]);
    u.v.z = pack2(src[4], src[5]); u.v.w = pack2(src[6], src[7]);
    unsigned long long* hq = (unsigned long long*)(ws + F_HF0);
    hq[(size_t)frag * 128u + l] = u.q[0];
    hq[(size_t)frag * 128u + 64u + l] = u.q[1];
  } else if (tid < 329728u) {
    unsigned int g = tid - 327680u;
    bias[g] = bih[g] + bhh[g];
  } else if (tid < 329744u) {
    __hip_atomic_store((unsigned int*)(ws + F_CTR) + (tid - 329728u) * 32u, 0u,
                       __ATOMIC_RELAXED, __HIP_MEMORY_SCOPE_AGENT);
  } else if (tid >= 331776u && tid < 4526080u) {
    unsigned int t2 = tid - 331776u;
    unsigned int frag = t2 >> 6, l = t2 & 63u;
    unsigned int ks = frag & 15u, mb = (frag >> 4) & 63u, t = frag >> 10;
    unsigned int b  = mb * 16u + (l & 15u);
    unsigned int k0 = ks * 32u + ((l >> 4) << 3);
    const float* src = xg + ((size_t)(b * 64u + t)) * 512u + k0;
    u32x4 p;
    p.x = pack2(src[0], src[1]); p.y = pack2(src[2], src[3]);
    p.z = pack2(src[4], src[5]); p.w = pack2(src[6], src[7]);
    *(u32x4*)(xbf + (size_t)frag * 512u + l * 8u) = p;
  }
}

// Big GEMM: x_proj[t] = x_t @ W_ih^T + bias, bf16 D-frag output.
// grid 8192 = t(64) x mtile(8) x ntile(16); tile 128M x 128N, K=512, BK=64.
__global__ void __launch_bounds__(256) gemm_xproj(unsigned char* __restrict__ ws) {
  const unsigned short* xbf = (const unsigned short*)(ws + F_XBF);
  const unsigned short* wih = (const unsigned short*)(ws + F_WIH);
  const float* bias = (const float*)(ws + F_BIAS);
  unsigned short* xproj = (unsigned short*)(ws + F_XPROJ);

  __shared__ __align__(16) unsigned char smem[65536];
  const int tid = threadIdx.x;
  const int w = tid >> 6, l = tid & 63;
  const int mh = w & 1, nh = w >> 1;
  const int bid = blockIdx.x;
  const int t = bid >> 7, mtile = (bid >> 4) & 7, ntile = bid & 15;

  f32x4 acc[4][4];
  {
    f32x4 z = {0.f, 0.f, 0.f, 0.f};
    #pragma unroll
    for (int i = 0; i < 4; ++i)
      #pragma unroll
      for (int j = 0; j < 4; ++j) acc[i][j] = z;
  }

  auto stage = [&](int kc, int buf) {
    unsigned char* ab = smem + buf * 16384;
    unsigned char* bb = smem + 32768 + buf * 16384;
    #pragma unroll
    for (int j = 0; j < 4; ++j) {
      int idx = w * 4 + j;
      int mb_l = idx >> 1, ksl = idx & 1;
      size_t frag = (size_t)(t * 64 + mtile * 8 + mb_l) * 16u + kc * 2 + ksl;
      gl_lds16(xbf + (frag * 64u + l) * 8u, ab + idx * 1024);
    }
    #pragma unroll
    for (int j = 0; j < 4; ++j) {
      int idx = w * 4 + j;
      int cb_l = idx >> 1, ksl = idx & 1;
      size_t frag = (size_t)(ntile * 8 + cb_l) * 16u + kc * 2 + ksl;
      gl_lds16(wih + (frag * 64u + l) * 8u, bb + idx * 1024);
    }
  };

  stage(0, 0);
  __syncthreads();
  for (int kc = 0; kc < 8; ++kc) {
    int cur = kc & 1;
    if (kc < 7) stage(kc + 1, cur ^ 1);
    unsigned char* ab = smem + cur * 16384;
    unsigned char* bb = smem + 32768 + cur * 16384;
    s16x8 afr[4][2], bfr[4][2];
    #pragma unroll
    for (int m = 0; m < 4; ++m)
      #pragma unroll
      for (int ksl = 0; ksl < 2; ++ksl)
        afr[m][ksl] = *(const s16x8*)(ab + ((mh * 4 + m) * 2 + ksl) * 1024 + l * 16);
    #pragma unroll
    for (int n = 0; n < 4; ++n)
      #pragma unroll
      for (int ksl = 0; ksl < 2; ++ksl)
        bfr[n][ksl] = *(const s16x8*)(bb + ((nh * 4 + n) * 2 + ksl) * 1024 + l * 16);
    #pragma unroll
    for (int m = 0; m < 4; ++m)
      #pragma unroll
      for (int n = 0; n < 4; ++n)
        #pragma unroll
        for (int ksl = 0; ksl < 2; ++ksl)
          acc[m][n] = __builtin_amdgcn_mfma_f32_16x16x32_bf16(
              afr[m][ksl], bfr[n][ksl], acc[m][n], 0, 0, 0);
    __syncthreads();
  }

  #pragma unroll
  for (int m = 0; m < 4; ++m) {
    int mb_abs = mtile * 8 + mh * 4 + m;
    #pragma unroll
    for (int n = 0; n < 4; ++n) {
      int n_abs = ntile * 8 + nh * 4 + n;
      float bc = bias[n_abs * 16 + (l & 15)];
      u16x4 p;
      #pragma unroll
      for (int r = 0; r < 4; ++r) p[r] = f2bf(acc[m][n][r] + bc);
      *(u16x4*)(xproj + ((size_t)(t * 64 + mb_abs) * 128u + n_abs) * 256u + l * 4u) = p;
    }
  }
}

// Persistent spin-barrier recurrence: 256 blocks x 512 threads, 1 block/CU.
// mt = blockIdx&15, ht = blockIdx>>4. Block: 64 rows x 32 h-cols.
// Wave w: (mbw=w>>1, cbl=w&1) -> 16 rows x 16 cols.
// LDS: [0,128K) W frags; Hl f32[64][36]; Cl f32[64][36]; dn16 bf16[64][72].
#define P_HL  131072
#define P_CL  140288
#define P_DN  149504
__global__ void __launch_bounds__(512, 2) persist_lock(
    const float* __restrict__ rnn, const float* __restrict__ dones,
    unsigned char* __restrict__ ws, float* __restrict__ out) {
  const unsigned short* whh = (const unsigned short*)(ws + F_WHH);
  const unsigned short* xproj = (const unsigned short*)(ws + F_XPROJ);
  unsigned int* ctrs = (unsigned int*)(ws + F_CTR);
  unsigned long long* hq0 = (unsigned long long*)(ws + F_HF0);
  unsigned long long* hq1 = (unsigned long long*)(ws + F_HF1);

  __shared__ __align__(16) unsigned char smem[158720];
  float* Hl = (float*)(smem + P_HL);
  float* Cl = (float*)(smem + P_CL);
  unsigned short* dn16 = (unsigned short*)(smem + P_DN);

  const int tid = threadIdx.x;
  const int w = tid >> 6, l = tid & 63;
  const int mbw = w >> 1, cbl = w & 1;
  const int mt = (int)blockIdx.x & 15, ht = (int)blockIdx.x >> 4;
  unsigned int* ctr = ctrs + mt * 32;

  // ---- prologue: W tile -> LDS, dones -> bf16 LDS, c0 -> regs ----
  #pragma unroll
  for (int j = 0; j < 16; ++j) {
    int idx = w * 16 + j;
    int gcb = idx >> 4, ks = idx & 15;
    int cb = (gcb >> 1) * 32 + ht * 2 + (gcb & 1);
    gl_lds16(whh + ((size_t)(cb * 16 + ks) * 64u + l) * 8u, smem + idx * 1024);
  }
  {
    const float* dsrc = dones + (size_t)mt * 4096u + tid * 8;
    f32x4 d0 = *(const f32x4*)dsrc, d1 = *(const f32x4*)(dsrc + 4);
    int row = tid >> 3, t0 = (tid & 7) * 8;
    u32x4 p;
    p.x = pack2(d0.x, d0.y); p.y = pack2(d0.z, d0.w);
    p.z = pack2(d1.x, d1.y); p.w = pack2(d1.z, d1.w);
    *(u32x4*)(dn16 + row * 72 + t0) = p;
  }
  f32x4 cold;
  #pragma unroll
  for (int r = 0; r < 4; ++r) {
    int b = mt * 64 + mbw * 16 + ((l >> 4) << 2) + r;
    cold[r] = rnn[(size_t)b * 1024u + 512u + ht * 32 + cbl * 16 + (l & 15)];
  }
  __syncthreads();

  // initial prefetch: areg(t=0) from hq0, xq(t=0)
  s16x8 areg[16];
  #pragma unroll
  for (int ks = 0; ks < 16; ++ks) {
    size_t f = (size_t)((mt * 4 + mbw) * 16 + ks) * 128u;
    union { unsigned long long q[2]; s16x8 v; } u;
    u.q[0] = __hip_atomic_load(hq0 + f + l, __ATOMIC_RELAXED, __HIP_MEMORY_SCOPE_AGENT);
    u.q[1] = __hip_atomic_load(hq0 + f + 64u + l, __ATOMIC_RELAXED, __HIP_MEMORY_SCOPE_AGENT);
    areg[ks] = u.v;
  }
  u16x4 xq[4];
  #pragma unroll
  for (int g = 0; g < 4; ++g) {
    int n_abs = g * 32 + ht * 2 + cbl;
    xq[g] = __builtin_nontemporal_load((const u16x4*)(xproj +
        ((size_t)(0 * 64 + mt * 4 + mbw) * 128u + n_abs) * 256u + l * 4u));
  }

  #pragma unroll 1
  for (int t = 0; t < 64; ++t) {
    // areg/xq hold step-t operands (prefetched)
    f32x4 acc[4];
    {
      f32x4 z = {0.f, 0.f, 0.f, 0.f};
      #pragma unroll
      for (int g = 0; g < 4; ++g) acc[g] = z;
    }
    #pragma unroll
    for (int ks = 0; ks < 16; ++ks) {
      s16x8 bfr[4];
      #pragma unroll
      for (int g = 0; g < 4; ++g)
        bfr[g] = *(const s16x8*)(smem + ((g * 2 + cbl) * 16 + ks) * 1024 + l * 16);
      #pragma unroll
      for (int g = 0; g < 4; ++g)
        acc[g] = __builtin_amdgcn_mfma_f32_16x16x32_bf16(areg[ks], bfr[g], acc[g], 0, 0, 0);
    }
    #pragma unroll
    for (int g = 0; g < 4; ++g)
      #pragma unroll
      for (int r = 0; r < 4; ++r) acc[g][r] += bf2f(xq[g][r]);

    // ---- LSTM cell (fast activations): h,c -> LDS; masked c -> regs ----
    #pragma unroll
    for (int r = 0; r < 4; ++r) {
      float gi = sigm_f(acc[0][r]);
      float gf = sigm_f(acc[1][r]);
      float gg = tanh_f(acc[2][r]);
      float go = sigm_f(acc[3][r]);
      int lrow = mbw * 16 + ((l >> 4) << 2) + r;
      float cc = gf * cold[r] + gi * gg;
      float h = go * tanh_f(cc);
      float keep = 1.0f - bf2f(dn16[lrow * 72 + t]);   // next step's mask
      cold[r] = cc * keep;
      Hl[lrow * 36 + cbl * 16 + (l & 15)] = h;
      Cl[lrow * 36 + cbl * 16 + (l & 15)] = cc;
    }
    __syncthreads();   // Hl/Cl complete

    if (t < 63) {
      // repack masked h -> hdst frags (SPLIT-u64 coherent stores)
      unsigned long long* hdst = (t & 1) ? hq0 : hq1;
      if (tid < 256) {
        const int mbl = tid >> 6, lp = tid & 63;
        const int row = mbl * 16 + (lp & 15);
        const float keep = 1.0f - bf2f(dn16[row * 72 + t]);
        const float* hr = Hl + (size_t)row * 36u + ((lp >> 4) << 3);
        union { u32x4 v; unsigned long long q[2]; } u;
        u.v.x = pack2(hr[0] * keep, hr[1] * keep);
        u.v.y = pack2(hr[2] * keep, hr[3] * keep);
        u.v.z = pack2(hr[4] * keep, hr[5] * keep);
        u.v.w = pack2(hr[6] * keep, hr[7] * keep);
        size_t f = (size_t)((mt * 4 + mbl) * 16 + ht) * 128u;
        __hip_atomic_store(hdst + f + lp, u.q[0],
                           __ATOMIC_RELAXED, __HIP_MEMORY_SCOPE_AGENT);
        __hip_atomic_store(hdst + f + 64u + lp, u.q[1],
                           __ATOMIC_RELAXED, __HIP_MEMORY_SCOPE_AGENT);
      }
      __syncthreads();   // per-wave vmcnt(0): repack stores at coherence point

      // arrive (tid0), then outputs (all waves), then per-wave spin
      if (tid == 0)
        __hip_atomic_fetch_add(ctr, 1u, __ATOMIC_RELEASE, __HIP_MEMORY_SCOPE_AGENT);
      {
        int row = tid >> 3, chn = tid & 7;
        int b = mt * 64 + row;
        f32x4 hv = *(const f32x4*)(Hl + row * 36 + chn * 4);
        f32x4 cv = *(const f32x4*)(Cl + row * 36 + chn * 4);
        int colg = ht * 32 + chn * 4;
        __builtin_nontemporal_store(hv, (f32x4*)(out + ((size_t)(b * 64 + t)) * 512u + colg));
        __builtin_nontemporal_store(hv, (f32x4*)(out + OUT_HS + ((size_t)(t * 1024 + b)) * 512u + colg));
        __builtin_nontemporal_store(cv, (f32x4*)(out + OUT_CS + ((size_t)(t * 1024 + b)) * 512u + colg));
      }
      // per-wave spin: each wave's lane0 polls, then the wave proceeds
      {
        unsigned int target = 16u * (unsigned int)(t + 1);
        if ((tid & 63) == 0) {
          while (__hip_atomic_load(ctr, __ATOMIC_ACQUIRE, __HIP_MEMORY_SCOPE_AGENT) < target)
            __builtin_amdgcn_s_sleep(1);
        }
      }
      // prefetch t+1 operands (A-frags from the just-published buffer + xproj)
      {
        const unsigned long long* hnxt = ((t + 1) & 1) ? hq1 : hq0;
        #pragma unroll
        for (int ks = 0; ks < 16; ++ks) {
          size_t f = (size_t)((mt * 4 + mbw) * 16 + ks) * 128u;
          union { unsigned long long q[2]; s16x8 v; } u;
          u.q[0] = __hip_atomic_load(hnxt + f + l, __ATOMIC_RELAXED, __HIP_MEMORY_SCOPE_AGENT);
          u.q[1] = __hip_atomic_load(hnxt + f + 64u + l, __ATOMIC_RELAXED, __HIP_MEMORY_SCOPE_AGENT);
          areg[ks] = u.v;
        }
        #pragma unroll
        for (int g = 0; g < 4; ++g) {
          int n_abs = g * 32 + ht * 2 + cbl;
          xq[g] = __builtin_nontemporal_load((const u16x4*)(xproj +
              ((size_t)((t + 1) * 64 + mt * 4 + mbw) * 128u + n_abs) * 256u + l * 4u));
        }
      }
      lds_barrier();   // join: Hl/Cl safe to reuse; vmem stores keep draining
    } else {
      // final step: outputs + rnn_states
      int row = tid >> 3, chn = tid & 7;
      int b = mt * 64 + row;
      f32x4 hv = *(const f32x4*)(Hl + row * 36 + chn * 4);
      f32x4 cv = *(const f32x4*)(Cl + row * 36 + chn * 4);
      int colg = ht * 32 + chn * 4;
      __builtin_nontemporal_store(hv, (f32x4*)(out + ((size_t)(b * 64 + t)) * 512u + colg));
      __builtin_nontemporal_store(hv, (f32x4*)(out + OUT_HS + ((size_t)(t * 1024 + b)) * 512u + colg));
      __builtin_nontemporal_store(cv, (f32x4*)(out + OUT_CS + ((size_t)(t * 1024 + b)) * 512u + colg));
      __builtin_nontemporal_store(hv, (f32x4*)(out + OUT_RNN + (size_t)b * 1024u + colg));
      __builtin_nontemporal_store(cv, (f32x4*)(out + OUT_RNN + (size_t)b * 1024u + 512u + colg));
    }
  }
}

// ====================== FALLBACK (round-1, verified) ======================

__global__ void __launch_bounds__(256) prep_kernel(
    const float* __restrict__ rnn, const float* __restrict__ Wih,
    const float* __restrict__ Whh, const float* __restrict__ bih,
    const float* __restrict__ bhh, unsigned char* __restrict__ ws) {
  unsigned int tid = blockIdx.x * 256u + threadIdx.x;
  unsigned short* wcf = (unsigned short*)(ws + WC_OFF);
  unsigned short* hf  = (unsigned short*)(ws + HF_OFF);
  float* cf   = (float*)(ws + CF_OFF);
  float* bias = (float*)(ws + BIAS_OFF);
  if (tid < 262144u) {
    unsigned int frag = tid >> 6, l = tid & 63u;
    unsigned int cb = frag >> 5, ks = frag & 31u;
    unsigned int g  = cb * 16u + (l & 15u);
    unsigned int k0 = ks * 32u + ((l >> 4) << 3);
    const float* src = (k0 < 512u) ? (Wih + g * 512u + k0) : (Whh + g * 512u + (k0 - 512u));
    u32x4 p;
    p.x = pack2(src[0], src[1]); p.y = pack2(src[2], src[3]);
    p.z = pack2(src[4], src[5]); p.w = pack2(src[6], src[7]);
    *(u32x4*)(wcf + (size_t)frag * 512u + l * 8u) = p;
  } else if (tid < 327680u) {
    unsigned int t2 = tid - 262144u;
    unsigned int frag = t2 >> 6, l = t2 & 63u;
    unsigned int mb = frag >> 4, ks = frag & 15u;
    unsigned int b  = mb * 16u + (l & 15u);
    unsigned int c0 = ks * 32u + ((l >> 4) << 3);
    const float* src = rnn + (size_t)b * 1024u + c0;
    u32x4 p;
    p.x = pack2(src[0], src[1]); p.y = pack2(src[2], src[3]);
    p.z = pack2(src[4], src[5]); p.w = pack2(src[6], src[7]);
    *(u32x4*)(hf + (size_t)frag * 512u + l * 8u) = p;
  } else if (tid < 458752u) {
    unsigned int t2 = tid - 327680u;
    unsigned int frag = t2 >> 6, l = t2 & 63u;
    unsigned int mb = frag >> 5, cfi = frag & 31u;
    unsigned int hcol = cfi * 16u + (l & 15u);
    f32x4 p;
    #pragma unroll
    for (int r = 0; r < 4; ++r) {
      unsigned int b = mb * 16u + ((l >> 4) << 2) + r;
      p[r] = rnn[(size_t)b * 1024u + 512u + hcol];
    }
    *(f32x4*)(cf + (size_t)frag * 256u + l * 4u) = p;
  } else if (tid < 460800u) {
    unsigned int g = tid - 458752u;
    bias[g] = bih[g] + bhh[g];
  }
}

__global__ void __launch_bounds__(256) step_kernel(
    const float* __restrict__ xg, const float* __restrict__ dones,
    unsigned char* __restrict__ ws, float* __restrict__ out, int t) {
  const unsigned short* wcf = (const unsigned short*)(ws + WC_OFF);
  unsigned short* hf = (unsigned short*)(ws + HF_OFF);
  float* cf = (float*)(ws + CF_OFF);
  const float* bias = (const float*)(ws + BIAS_OFF);

  __shared__ __align__(16) unsigned char smem[49152];
  const int tid = threadIdx.x;
  const int w = tid >> 6, l = tid & 63;
  const int mh = w & 1, ch = w >> 1;
  const int mt = (int)blockIdx.x >> 4, ht = (int)blockIdx.x & 15;

  f32x4 acc[2][4];
  {
    f32x4 z = {0.f, 0.f, 0.f, 0.f};
    #pragma unroll
    for (int i = 0; i < 2; ++i)
      #pragma unroll
      for (int j = 0; j < 4; ++j) acc[i][j] = z;
  }

  f32x4 xv[2][2];

  auto stage_load = [&](int kc, int buf) {
    unsigned char* bb = smem + 16384 + buf * 16384;
    #pragma unroll
    for (int j = 0; j < 4; ++j) {
      int idx = w * 4 + j;
      int g = idx >> 2, cbl = (idx >> 1) & 1, ksl = idx & 1;
      int cb = g * 32 + ht * 2 + cbl;
      int ks = kc * 2 + ksl;
      const unsigned short* src = wcf + ((size_t)(cb * 32 + ks) * 64u + l) * 8u;
      gl_lds16(src, bb + idx * 1024);
    }
    unsigned char* ab = smem + buf * 8192;
    if (kc >= 8) {
      #pragma unroll
      for (int j = 0; j < 2; ++j) {
        int idx = w * 2 + j;
        int ksh = (kc - 8) * 2 + j;
        int mb_abs = mt * 4 + w;
        const unsigned short* src = hf + ((size_t)(mb_abs * 16 + ksh) * 64u + l) * 8u;
        gl_lds16(src, ab + idx * 1024);
      }
    } else {
      #pragma unroll
      for (int j = 0; j < 2; ++j) {
        int ks = kc * 2 + j;
        int b = mt * 64 + w * 16 + (l & 15);
        int k0 = ks * 32 + ((l >> 4) << 3);
        const float* src = xg + ((size_t)(b * 64 + t)) * 512u + k0;
        xv[j][0] = *(const f32x4*)src;
        xv[j][1] = *(const f32x4*)(src + 4);
      }
    }
  };
  auto stage_write = [&](int kc, int buf) {
    if (kc < 8) {
      unsigned char* ab = smem + buf * 8192;
      #pragma unroll
      for (int j = 0; j < 2; ++j) {
        int idx = w * 2 + j;
        u32x4 p;
        p.x = pack2(xv[j][0].x, xv[j][0].y); p.y = pack2(xv[j][0].z, xv[j][0].w);
        p.z = pack2(xv[j][1].x, xv[j][1].y); p.w = pack2(xv[j][1].z, xv[j][1].w);
        *(u32x4*)(ab + idx * 1024 + l * 16) = p;
      }
    }
  };

  stage_load(0, 0);
  stage_write(0, 0);
  __syncthreads();

  for (int kc = 0; kc < 16; ++kc) {
    int cur = kc & 1;
    if (kc < 15) stage_load(kc + 1, cur ^ 1);
    unsigned char* ab = smem + cur * 8192;
    unsigned char* bb = smem + 16384 + cur * 16384;
    s16x8 afr[2][2], bfr[4][2];
    #pragma unroll
    for (int mb2 = 0; mb2 < 2; ++mb2)
      #pragma unroll
      for (int ksl = 0; ksl < 2; ++ksl)
        afr[mb2][ksl] = *(const s16x8*)(ab + ((mh * 2 + mb2) * 2 + ksl) * 1024 + l * 16);
    #pragma unroll
    for (int g = 0; g < 4; ++g)
      #pragma unroll
      for (int ksl = 0; ksl < 2; ++ksl)
        bfr[g][ksl] = *(const s16x8*)(bb + (g * 4 + ch * 2 + ksl) * 1024 + l * 16);
    #pragma unroll
    for (int mb2 = 0; mb2 < 2; ++mb2)
      #pragma unroll
      for (int g = 0; g < 4; ++g)
        #pragma unroll
        for (int ksl = 0; ksl < 2; ++ksl)
          acc[mb2][g] = __builtin_amdgcn_mfma_f32_16x16x32_bf16(
              afr[mb2][ksl], bfr[g][ksl], acc[mb2][g], 0, 0, 0);
    if (kc < 15) stage_write(kc + 1, cur ^ 1);
    __syncthreads();
  }

  const int hcol = ht * 32 + ch * 16 + (l & 15);
  const float bi = bias[hcol], bf2 = bias[512 + hcol];
  const float bg = bias[1024 + hcol], bo = bias[1536 + hcol];
  float* Hl = (float*)smem;
  float* Cl = (float*)(smem + 9216);
  const int cfi = ht * 2 + ch;
  const int colL = ch * 16 + (l & 15);
  #pragma unroll
  for (int mb2 = 0; mb2 < 2; ++mb2) {
    const int mb_abs = mt * 4 + mh * 2 + mb2;
    const int fid = mb_abs * 32 + cfi;
    f32x4 cold = *(const f32x4*)(cf + (size_t)fid * 256u + l * 4u);
    f32x4 cmask;
    #pragma unroll
    for (int r = 0; r < 4; ++r) {
      float gi = sigm(acc[mb2][0][r] + bi);
      float gf = sigm(acc[mb2][1][r] + bf2);
      float gg = tanhf(acc[mb2][2][r] + bg);
      float go = sigm(acc[mb2][3][r] + bo);
      float c = gf * cold[r] + gi * gg;
      float h = go * tanhf(c);
      int brow = mb_abs * 16 + ((l >> 4) << 2) + r;
      float keep = 1.0f - dones[brow * 64 + t];
      cmask[r] = c * keep;
      int rowL = mh * 32 + mb2 * 16 + ((l >> 4) << 2) + r;
      Hl[rowL * 36 + colL] = h;
      Cl[rowL * 36 + colL] = c;
    }
    *(f32x4*)(cf + (size_t)fid * 256u + l * 4u) = cmask;
  }
  __syncthreads();

  {
    const int mb2f = tid >> 6, lp = tid & 63;
    const int mb_abs = mt * 4 + mb2f;
    const int rowL = mb2f * 16 + (lp & 15);
    const int c0 = (lp >> 4) << 3;
    const int brow = mt * 64 + rowL;
    const float keep = 1.0f - dones[brow * 64 + t];
    const float* hr = Hl + rowL * 36 + c0;
    u32x4 p;
    p.x = pack2(hr[0] * keep, hr[1] * keep);
    p.y = pack2(hr[2] * keep, hr[3] * keep);
    p.z = pack2(hr[4] * keep, hr[5] * keep);
    p.w = pack2(hr[6] * keep, hr[7] * keep);
    *(u32x4*)(hf + ((size_t)(mb_abs * 16 + ht) * 64u + lp) * 8u) = p;
  }
  {
    const int row = tid & 63, cg2 = tid >> 6;
    const int b = mt * 64 + row;
    const int c0 = cg2 * 8;
    const float* hr = Hl + row * 36 + c0;
    const float* cr = Cl + row * 36 + c0;
    f32x4 h0 = *(const f32x4*)hr,  h1 = *(const f32x4*)(hr + 4);
    f32x4 cc0 = *(const f32x4*)cr, cc1 = *(const f32x4*)(cr + 4);
    const int colg = ht * 32 + c0;
    size_t xoff = ((size_t)(b * 64 + t)) * 512u + colg;
    *(f32x4*)(out + xoff) = h0; *(f32x4*)(out + xoff + 4) = h1;
    size_t hoff = OUT_HS + ((size_t)(t * 1024 + b)) * 512u + colg;
    *(f32x4*)(out + hoff) = h0; *(f32x4*)(out + hoff + 4) = h1;
    size_t coff = OUT_CS + ((size_t)(t * 1024 + b)) * 512u + colg;
    *(f32x4*)(out + coff) = cc0; *(f32x4*)(out + coff + 4) = cc1;
    if (t == 63) {
      size_t roff = OUT_RNN + (size_t)b * 1024u + colg;
      *(f32x4*)(out + roff) = h0;        *(f32x4*)(out + roff + 4) = h1;
      *(f32x4*)(out + roff + 512) = cc0; *(f32x4*)(out + roff + 516) = cc1;
    }
  }
}

extern "C" void kernel_launch(void* const* d_in, const int* in_sizes, int n_in,
                              void* d_out, int out_size, void* d_ws, size_t ws_size,
                              hipStream_t stream) {
  const float* xg  = (const float*)d_in[0];
  const float* rnn = (const float*)d_in[1];
  const float* dn  = (const float*)d_in[2];
  const float* Wih = (const float*)d_in[3];
  const float* Whh = (const float*)d_in[4];
  const float* bih = (const float*)d_in[5];
  const float* bhh = (const float*)d_in[6];
  float* out = (float*)d_out;
  unsigned char* ws = (unsigned char*)d_ws;
  (void)in_sizes; (void)n_in; (void)out_size;

  if (ws_size >= (size_t)F_NEED) {
    prep_fast<<<17680, 256, 0, stream>>>(xg, rnn, Wih, Whh, bih, bhh, ws);
    gemm_xproj<<<8192, 256, 0, stream>>>(ws);
    persist_lock<<<256, 512, 0, stream>>>(rnn, dn, ws, out);
  } else {
    prep_kernel<<<1800, 256, 0, stream>>>(rnn, Wih, Whh, bih, bhh, ws);
    for (int t = 0; t < 64; ++t)
      step_kernel<<<256, 256, 0, stream>>>(xg, dn, ws, out, t);
  }
}